// Round 6
// baseline (174.512 us; speedup 1.0000x reference)
//
#include <hip/hip_runtime.h>
#include <hip/hip_bf16.h>

#define NOBJ 25

typedef short bf16x8 __attribute__((ext_vector_type(8)));
typedef float f32x4 __attribute__((ext_vector_type(4)));

__device__ __forceinline__ short f2bf(float f) {
  __hip_bfloat16 b = __float2bfloat16(f);  // RTN
  return *reinterpret_cast<short*>(&b);
}
__device__ __forceinline__ float bf2f(short s) {
  unsigned u = ((unsigned)(unsigned short)s) << 16;
  return __uint_as_float(u);
}

// ---------------------------------------------------------------------------
// prep: MLP weights -> hi/lo bf16, fragment-linear.
// Per layer L in {0,1} at L*131072: [term][nt][ks][lane][j];
// layer 3 at 262144: [term][ks][lane][j], cols>=10 zero-padded (term stride 4096).
// value = w[(nt*16+(lane&15))*256 + ks*32 + (lane>>4)*8 + j]
// 264 blocks x 256 threads x 4 iters = 270336 exactly.
// ---------------------------------------------------------------------------
__global__ __launch_bounds__(256) void prep_kernel(
    const float* __restrict__ w1, const float* __restrict__ w2,
    const float* __restrict__ w3, short* __restrict__ wfm) {
  for (int j = blockIdx.x * 256 + threadIdx.x; j < 270336; j += 264 * 256) {
    const float* w; int term, f, nt;
    const bool isw3 = (j >= 262144);
    if (!isw3) {
      w = (j >> 17) ? w2 : w1;
      const int idx = j & 131071;
      term = idx >> 16; f = idx & 65535; nt = f >> 12;
    } else {
      w = w3;
      const int idx = j - 262144;  // 0..8191
      term = idx >> 12; f = idx & 4095; nt = 0;
    }
    const int ks = (f >> 9) & 7;
    const int l  = (f >> 3) & 63;
    const int jj = f & 7;
    const int col = nt * 16 + (l & 15);
    const int k   = ks * 32 + (l >> 4) * 8 + jj;
    const float v = (isw3 && col >= 10) ? 0.f : w[col * 256 + k];
    const short hi = f2bf(v);
    wfm[j] = (term == 0) ? hi : f2bf(v - bf2f(hi));
  }
}

// ---------------------------------------------------------------------------
// Fused kernel: conv taps (MFMA) + pairwise relu-pool + 3-layer MFMA MLP.
// 256 blocks x 512 threads (8 waves); block owns samples n0..n0+3.
//
// Conv: wave wv owns channels [32wv, 32wv+32) for ALL 4 samples (sequential).
//   - Wf (2 taps x 2 ntiles x 2 ks) converted inline from f32: 32 VGPR.
//   - Xf fragments loaded directly from global x (L1-shared across waves),
//     row-clamped to 24 (rows 25..31 duplicate row 24; outputs never read).
//   - 16 MFMAs/sample -> scatter to wave-private ab[2][25][34] (pitch 34:
//     reads broadcast across lane halves, writes <=2-way).
//   - pairwise: lane = (half = lane>>5, ch = lane&31); half h sums pairs with
//     i === h (mod 2); combine via shfl_xor(32). ~460 VALU ops/lane/sample.
// Then ONE barrier, ab is dead -> overlay H (hi/lo bf16 [pp][term][4][272]),
// and the MLP runs in-block (M=4 rows, wave wv owns cols [32wv,32wv+32)),
// weights streamed fragment-linear from L2, bulk-loaded before the MFMAs.
// ---------------------------------------------------------------------------
__global__ __launch_bounds__(512) void fused_kernel(
    const float* __restrict__ x,    // (1024, 25*64)
    const float* __restrict__ cw0,  // (256, 64)
    const float* __restrict__ cw1,  // (256, 64)
    const float* __restrict__ cb,   // (256)
    const short* __restrict__ wfm,  // fragment-linear hi/lo MLP weights
    const float* __restrict__ b1, const float* __restrict__ b2,
    const float* __restrict__ b3,
    float* __restrict__ out)        // (1024, 10)
{
  __shared__ __align__(16) float ab[8][2][NOBJ][34];  // 54400 B, per-wave scratch
  short* Hs = reinterpret_cast<short*>(&ab[0][0][0][0]);  // overlay after barrier
  // Hs layout: [pp][term][row 4][272] shorts; idx=((pp*2+term)*4+row)*272+col

  const int t = threadIdx.x, lane = t & 63, wv = t >> 6;
  const int r = lane & 15, g = lane >> 4;
  const int n0 = blockIdx.x * 4;
  const int chbase = wv * 32;

  // ---- conv phase ----
  bf16x8 Wf[2][2][2];  // [tap][ntl2][ks]
#pragma unroll
  for (int tap = 0; tap < 2; ++tap) {
    const float* wsrc = tap ? cw1 : cw0;
#pragma unroll
    for (int ntl = 0; ntl < 2; ++ntl)
#pragma unroll
      for (int ks = 0; ks < 2; ++ks) {
        const int ch = chbase + ntl * 16 + r;
        const float* p = wsrc + ch * 64 + ks * 32 + g * 8;
        const float4 a = *reinterpret_cast<const float4*>(p);
        const float4 b = *reinterpret_cast<const float4*>(p + 4);
        bf16x8 fr;
        fr[0] = f2bf(a.x); fr[1] = f2bf(a.y); fr[2] = f2bf(a.z); fr[3] = f2bf(a.w);
        fr[4] = f2bf(b.x); fr[5] = f2bf(b.y); fr[6] = f2bf(b.z); fr[7] = f2bf(b.w);
        Wf[tap][ntl][ks] = fr;
      }
  }
  float cbv[2];
#pragma unroll
  for (int ntl = 0; ntl < 2; ++ntl) cbv[ntl] = cb[chbase + ntl * 16 + r];

  float* abw = &ab[wv][0][0][0];  // [tap*850 + obj*34 + chl]
  const int half = lane >> 5, ch = lane & 31;
  float hreg[4];

#pragma unroll 1
  for (int s = 0; s < 4; ++s) {
    const int n = n0 + s;
    // X fragments direct from global (row-clamped; clamped rows' outputs unread)
    bf16x8 Xf[2][2];
#pragma unroll
    for (int mt = 0; mt < 2; ++mt) {
      const int row = mt * 16 + r;
      const int rowc = row > 24 ? 24 : row;
#pragma unroll
      for (int ks = 0; ks < 2; ++ks) {
        const float* px = x + (size_t)n * 1600 + rowc * 64 + ks * 32 + g * 8;
        const float4 a = *reinterpret_cast<const float4*>(px);
        const float4 b = *reinterpret_cast<const float4*>(px + 4);
        bf16x8 fr;
        fr[0] = f2bf(a.x); fr[1] = f2bf(a.y); fr[2] = f2bf(a.z); fr[3] = f2bf(a.w);
        fr[4] = f2bf(b.x); fr[5] = f2bf(b.y); fr[6] = f2bf(b.z); fr[7] = f2bf(b.w);
        Xf[mt][ks] = fr;
      }
    }

    f32x4 acc[2][2][2];  // [tap][mt][ntl2]
#pragma unroll
    for (int tap = 0; tap < 2; ++tap)
#pragma unroll
      for (int mt = 0; mt < 2; ++mt)
#pragma unroll
        for (int ntl = 0; ntl < 2; ++ntl) {
          f32x4 z = {0.f, 0.f, 0.f, 0.f};
          acc[tap][mt][ntl] = z;
        }
#pragma unroll
    for (int tap = 0; tap < 2; ++tap)
#pragma unroll
      for (int mt = 0; mt < 2; ++mt)
#pragma unroll
        for (int ntl = 0; ntl < 2; ++ntl)
#pragma unroll
          for (int ks = 0; ks < 2; ++ks)
            acc[tap][mt][ntl] = __builtin_amdgcn_mfma_f32_16x16x32_bf16(
                Xf[mt][ks], Wf[tap][ntl][ks], acc[tap][mt][ntl], 0, 0, 0);

    // scatter to wave-private ab (D: col=lane&15 -> channel, row=4g+q -> object)
#pragma unroll
    for (int tap = 0; tap < 2; ++tap)
#pragma unroll
      for (int mt = 0; mt < 2; ++mt)
#pragma unroll
        for (int ntl = 0; ntl < 2; ++ntl) {
          const int chl = ntl * 16 + r;
          const int row0 = mt * 16 + g * 4;
          const float badd = (tap == 0) ? cbv[ntl] : 0.f;
#pragma unroll
          for (int q = 0; q < 4; ++q)
            if (row0 + q < NOBJ)
              abw[tap * 850 + (row0 + q) * 34 + chl] = acc[tap][mt][ntl][q] + badd;
        }
    // same-wave LDS RAW: in-order per wave (verified pattern, R5 passed)

    float A[NOBJ], Bv[NOBJ];
#pragma unroll
    for (int i = 0; i < NOBJ; ++i) {
      A[i]  = abw[i * 34 + ch];          // broadcast across lane halves
      Bv[i] = abw[850 + i * 34 + ch];
    }
    float hacc = 0.f;
#pragma unroll
    for (int d = 1; d < NOBJ; ++d) {
      float sd = 0.f;
#pragma unroll
      for (int i = half; i + d < NOBJ; i += 2)
        sd += fmaxf(A[i] + Bv[i + d], 0.f);
      hacc = __builtin_fmaf(sd, 1.0f / (float)(NOBJ - d), hacc);
    }
    hacc += __shfl_xor(hacc, 32);
    hreg[s] = hacc * (1.0f / (float)(NOBJ - 1));
  }

  __syncthreads();  // all waves done with ab -> safe to overlay H

  if (lane < 32) {  // lanes 0..31 hold valid h for channels chbase+ch
#pragma unroll
    for (int s = 0; s < 4; ++s) {
      const float v = hreg[s];
      const short hi = f2bf(v);
      const short lo = f2bf(v - bf2f(hi));
      const int col = chbase + ch;
      Hs[((0 * 2 + 0) * 4 + s) * 272 + col] = hi;
      Hs[((0 * 2 + 1) * 4 + s) * 272 + col] = lo;
    }
  }
  __syncthreads();

  // ---- MLP phase: M=4 rows, wave wv owns cols [32wv, 32wv+32) ----
  int pp = 0;
  const float* bias[2] = {b1, b2};
#pragma unroll
  for (int L = 0; L < 2; ++L) {
    const short* wl = wfm + L * 131072;

    bf16x8 ahi[8], alo[8];
#pragma unroll
    for (int ks = 0; ks < 8; ++ks) {
      const int ko = ks * 32 + g * 8;
      ahi[ks] = *reinterpret_cast<const bf16x8*>(&Hs[((pp * 2 + 0) * 4 + (r & 3)) * 272 + ko]);
      alo[ks] = *reinterpret_cast<const bf16x8*>(&Hs[((pp * 2 + 1) * 4 + (r & 3)) * 272 + ko]);
    }

    f32x4 acc[2];
#pragma unroll
    for (int ntl = 0; ntl < 2; ++ntl) {
      const float bv = bias[L][wv * 32 + ntl * 16 + r];
      f32x4 a = {bv, bv, bv, bv};
      acc[ntl] = a;
    }

    {  // hi-B bulk load, then 32 MFMAs (ahi*bhi + alo*bhi)
      bf16x8 bh[2][8];
#pragma unroll
      for (int ntl = 0; ntl < 2; ++ntl)
#pragma unroll
        for (int ks = 0; ks < 8; ++ks)
          bh[ntl][ks] = *reinterpret_cast<const bf16x8*>(
              wl + (((wv * 2 + ntl) * 8 + ks) << 9) + lane * 8);
#pragma unroll
      for (int ks = 0; ks < 8; ++ks)
#pragma unroll
        for (int ntl = 0; ntl < 2; ++ntl) {
          acc[ntl] = __builtin_amdgcn_mfma_f32_16x16x32_bf16(ahi[ks], bh[ntl][ks], acc[ntl], 0, 0, 0);
          acc[ntl] = __builtin_amdgcn_mfma_f32_16x16x32_bf16(alo[ks], bh[ntl][ks], acc[ntl], 0, 0, 0);
        }
    }
    {  // lo-B bulk load, then 16 MFMAs (ahi*blo)
      bf16x8 bl[2][8];
#pragma unroll
      for (int ntl = 0; ntl < 2; ++ntl)
#pragma unroll
        for (int ks = 0; ks < 8; ++ks)
          bl[ntl][ks] = *reinterpret_cast<const bf16x8*>(
              wl + 65536 + (((wv * 2 + ntl) * 8 + ks) << 9) + lane * 8);
#pragma unroll
      for (int ks = 0; ks < 8; ++ks)
#pragma unroll
        for (int ntl = 0; ntl < 2; ++ntl)
          acc[ntl] = __builtin_amdgcn_mfma_f32_16x16x32_bf16(ahi[ks], bl[ntl][ks], acc[ntl], 0, 0, 0);
    }

    __syncthreads();  // everyone done reading Hs[pp] before overwrite check
    if (g == 0) {     // D rows 0..3 = samples; rows 4..15 are duplicates
#pragma unroll
      for (int ntl = 0; ntl < 2; ++ntl) {
        const int col = wv * 32 + ntl * 16 + r;
#pragma unroll
        for (int q = 0; q < 4; ++q) {
          const float v = fmaxf(acc[ntl][q], 0.f);
          const short hi = f2bf(v);
          Hs[(((pp ^ 1) * 2 + 0) * 4 + q) * 272 + col] = hi;
          Hs[(((pp ^ 1) * 2 + 1) * 4 + q) * 272 + col] = f2bf(v - bf2f(hi));
        }
      }
    }
    __syncthreads();
    pp ^= 1;
  }

  // layer 3: one 16x16 tile (cols 10..15 zero-padded), wave 0 only
  if (wv == 0) {
    const float bv = (r < 10) ? b3[r] : 0.f;
    f32x4 acc = {bv, bv, bv, bv};
    bf16x8 ahi[8], alo[8], bh[8], bl[8];
#pragma unroll
    for (int ks = 0; ks < 8; ++ks) {
      const int ko = ks * 32 + g * 8;
      ahi[ks] = *reinterpret_cast<const bf16x8*>(&Hs[((pp * 2 + 0) * 4 + (r & 3)) * 272 + ko]);
      alo[ks] = *reinterpret_cast<const bf16x8*>(&Hs[((pp * 2 + 1) * 4 + (r & 3)) * 272 + ko]);
      bh[ks] = *reinterpret_cast<const bf16x8*>(wfm + 262144 + (ks << 9) + lane * 8);
      bl[ks] = *reinterpret_cast<const bf16x8*>(wfm + 262144 + 4096 + (ks << 9) + lane * 8);
    }
#pragma unroll
    for (int ks = 0; ks < 8; ++ks) {
      acc = __builtin_amdgcn_mfma_f32_16x16x32_bf16(ahi[ks], bh[ks], acc, 0, 0, 0);
      acc = __builtin_amdgcn_mfma_f32_16x16x32_bf16(alo[ks], bh[ks], acc, 0, 0, 0);
      acc = __builtin_amdgcn_mfma_f32_16x16x32_bf16(ahi[ks], bl[ks], acc, 0, 0, 0);
    }
    if (g == 0 && r < 10) {  // rows 0..3 = samples
#pragma unroll
      for (int q = 0; q < 4; ++q)
        out[(size_t)(n0 + q) * 10 + r] = acc[q];
    }
  }
}

extern "C" void kernel_launch(void* const* d_in, const int* in_sizes, int n_in,
                              void* d_out, int out_size, void* d_ws, size_t ws_size,
                              hipStream_t stream) {
  const float* x   = (const float*)d_in[0];
  const float* cw0 = (const float*)d_in[1];
  const float* cw1 = (const float*)d_in[2];
  const float* cb  = (const float*)d_in[3];
  const float* w1  = (const float*)d_in[4];
  const float* b1  = (const float*)d_in[5];
  const float* w2  = (const float*)d_in[6];
  const float* b2  = (const float*)d_in[7];
  const float* w3  = (const float*)d_in[8];
  const float* b3  = (const float*)d_in[9];
  float* out = (float*)d_out;

  short* wfm = (short*)d_ws;  // 540 KB: fragment-linear hi/lo MLP weights

  prep_kernel<<<264, 256, 0, stream>>>(w1, w2, w3, wfm);
  fused_kernel<<<256, 512, 0, stream>>>(x, cw0, cw1, cb, wfm, b1, b2, b3, out);
}

// Round 7
// 37.318 us; speedup vs baseline: 4.6764x; 4.6764x over previous
//
#include <hip/hip_runtime.h>
#include <hip/hip_bf16.h>

#define NOBJ 25

typedef short bf16x8 __attribute__((ext_vector_type(8)));
typedef short s16x4 __attribute__((ext_vector_type(4)));
typedef float f32x4 __attribute__((ext_vector_type(4)));

__device__ __forceinline__ short f2bf(float f) {
  __hip_bfloat16 b = __float2bfloat16(f);  // RTN
  return *reinterpret_cast<short*>(&b);
}
__device__ __forceinline__ float bf2f(short s) {
  unsigned u = ((unsigned)(unsigned short)s) << 16;
  return __uint_as_float(u);
}

// ---------------------------------------------------------------------------
// K1: blocks 0..127  : MLP weight prep (hi/lo bf16, fragment-linear) — runs
//                      FIRST so it overlaps conv instead of a serialized tail.
//     blocks 128..639: conv taps via bf16 MFMA + wave-local pairwise pool,
//                      2 samples/block (R5 structure, pairwise re-done).
// Pairwise register discipline (the R2-R6 20us bug): only Bv[25] is held
// resident; A is streamed one element per i; per-term weight folded into an
// fma. All loop bounds compile-time -> full unroll -> static indexing ->
// peak ~120 VGPR. launch_bounds(256,2) allows 256 VGPR so the allocator
// doesn't demote arrays to scratch/LDS-refetch chasing occupancy.
// ---------------------------------------------------------------------------
__global__ __launch_bounds__(256, 2) void conv_prep_kernel(
    const float* __restrict__ x,    // (1024, 25*64)
    const float* __restrict__ cw0,  // (256, 64)
    const float* __restrict__ cw1,  // (256, 64)
    const float* __restrict__ cb,   // (256)
    const float* __restrict__ w1, const float* __restrict__ w2,
    const float* __restrict__ w3,
    float* __restrict__ h,          // (1024, 256)
    short* __restrict__ wfm)        // 270336 shorts, fragment-linear hi/lo
{
  __shared__ short xs[2][32][72];        // 9216 B
  __shared__ float ab[4][2][NOBJ][68];   // 54400 B (per-wave scratch)

  if (blockIdx.x < 128) {
    // ---- MLP weight prep: layer L at L*131072: [term][nt][ks][lane][j];
    // layer 3 at 262144: [term][ks][lane][j], cols>=10 zero-padded.
    // value = w[(nt*16+(lane&15))*256 + ks*32 + (lane>>4)*8 + j]
    for (int j = blockIdx.x * 256 + threadIdx.x; j < 270336; j += 128 * 256) {
      const float* w; int term, f, nt;
      const bool isw3 = (j >= 262144);
      if (!isw3) {
        w = (j >> 17) ? w2 : w1;
        const int idx = j & 131071;
        term = idx >> 16; f = idx & 65535; nt = f >> 12;
      } else {
        w = w3;
        const int idx = j - 262144;  // 0..8191
        term = idx >> 12; f = idx & 4095; nt = 0;
      }
      const int ks = (f >> 9) & 7;
      const int l  = (f >> 3) & 63;
      const int jj = f & 7;
      const int col = nt * 16 + (l & 15);
      const int k   = ks * 32 + (l >> 4) * 8 + jj;
      const float v = (isw3 && col >= 10) ? 0.f : w[col * 256 + k];
      const short hi = f2bf(v);
      wfm[j] = (term == 0) ? hi : f2bf(v - bf2f(hi));
    }
    return;
  }

  // ---- conv branch ----
  const int t = threadIdx.x;
  const int lane = t & 63;
  const int wv = t >> 6;
  const int r = lane & 15;
  const int g = lane >> 4;
  const int n0 = (blockIdx.x - 128) * 2;

  // W fragments for both taps, converted inline from f32 (one-time).
  bf16x8 Wf[2][4][2];  // [tap][ntile][kstep]
#pragma unroll
  for (int tap = 0; tap < 2; ++tap) {
    const float* wsrc = tap ? cw1 : cw0;
#pragma unroll
    for (int ntl = 0; ntl < 4; ++ntl)
#pragma unroll
      for (int ks = 0; ks < 2; ++ks) {
        const int ch = wv * 64 + ntl * 16 + r;
        const float* p = wsrc + ch * 64 + ks * 32 + g * 8;
        const float4 a = *reinterpret_cast<const float4*>(p);
        const float4 b = *reinterpret_cast<const float4*>(p + 4);
        bf16x8 fr;
        fr[0] = f2bf(a.x); fr[1] = f2bf(a.y); fr[2] = f2bf(a.z); fr[3] = f2bf(a.w);
        fr[4] = f2bf(b.x); fr[5] = f2bf(b.y); fr[6] = f2bf(b.z); fr[7] = f2bf(b.w);
        Wf[tap][ntl][ks] = fr;
      }
  }
  float cbv[4];
#pragma unroll
  for (int ntl = 0; ntl < 4; ++ntl) cbv[ntl] = cb[wv * 64 + ntl * 16 + r];

  // cooperative x staging (both samples) -> single barrier
  for (int s = 0; s < 2; ++s) {
    const float4* xg = reinterpret_cast<const float4*>(x + (size_t)(n0 + s) * (NOBJ * 64));
    for (int i = t; i < 400; i += 256) {
      float4 v = xg[i];
      s16x4 p;
      p.x = f2bf(v.x); p.y = f2bf(v.y); p.z = f2bf(v.z); p.w = f2bf(v.w);
      *reinterpret_cast<s16x4*>(&xs[s][i >> 4][(i & 15) * 4]) = p;
    }
  }
  __syncthreads();

  for (int s = 0; s < 2; ++s) {
    bf16x8 Xf[2][2];  // [mtile][kstep]; rows 25..31 garbage, never read out
#pragma unroll
    for (int mt = 0; mt < 2; ++mt)
#pragma unroll
      for (int ks = 0; ks < 2; ++ks)
        Xf[mt][ks] = *reinterpret_cast<const bf16x8*>(&xs[s][mt * 16 + r][ks * 32 + g * 8]);

    f32x4 acc[2][2][4];  // [tap][mtile][ntile]
#pragma unroll
    for (int tap = 0; tap < 2; ++tap)
#pragma unroll
      for (int mt = 0; mt < 2; ++mt)
#pragma unroll
        for (int ntl = 0; ntl < 4; ++ntl) {
          f32x4 z = {0.f, 0.f, 0.f, 0.f};
          acc[tap][mt][ntl] = z;
        }

#pragma unroll
    for (int tap = 0; tap < 2; ++tap)
#pragma unroll
      for (int mt = 0; mt < 2; ++mt)
#pragma unroll
        for (int ntl = 0; ntl < 4; ++ntl)
#pragma unroll
          for (int ks = 0; ks < 2; ++ks)
            acc[tap][mt][ntl] = __builtin_amdgcn_mfma_f32_16x16x32_bf16(
                Xf[mt][ks], Wf[tap][ntl][ks], acc[tap][mt][ntl], 0, 0, 0);

    // wave-local scatter (D: col=lane&15 -> channel, row=4*(lane>>4)+q -> object)
#pragma unroll
    for (int tap = 0; tap < 2; ++tap)
#pragma unroll
      for (int mt = 0; mt < 2; ++mt)
#pragma unroll
        for (int ntl = 0; ntl < 4; ++ntl) {
          const int cl = ntl * 16 + r;
          const int row0 = mt * 16 + g * 4;
          const float badd = (tap == 0) ? cbv[ntl] : 0.f;
#pragma unroll
          for (int q = 0; q < 4; ++q)
            if (row0 + q < NOBJ) ab[wv][tap][row0 + q][cl] = acc[tap][mt][ntl][q] + badd;
        }
    // same-wave LDS RAW ordered by lgkmcnt; ab is wave-private -> no barrier

    // pairwise: lane = channel. Bv resident (25 regs), A streamed per i,
    // weight folded into fma (all bounds static -> full unroll).
    float Bv[NOBJ];
#pragma unroll
    for (int i = 0; i < NOBJ; ++i) Bv[i] = ab[wv][1][i][lane];
    float h0 = 0.f, h1 = 0.f;
#pragma unroll
    for (int i = 0; i < NOBJ - 1; ++i) {
      const float a = ab[wv][0][i][lane];
      float sacc = 0.f;
#pragma unroll
      for (int j = i + 1; j < NOBJ; ++j)
        sacc = __builtin_fmaf(fmaxf(a + Bv[j], 0.f),
                              1.0f / (float)(NOBJ - (j - i)), sacc);
      if (i & 1) h1 += sacc; else h0 += sacc;
    }
    h[(size_t)(n0 + s) * 256 + t] = (h0 + h1) * (1.0f / (float)(NOBJ - 1));
  }
}

// ---------------------------------------------------------------------------
// K2: fused 3-layer MLP, bf16 MFMA hi/lo split (3 terms). 256 blocks x 512
// threads (1 block/CU, 2 waves/SIMD, ALL CUs stream weights -> ~3.7us L2
// floor). Block owns M=4 rows; wave wv owns cols [32wv, 32wv+32)
// (nt = wv*2+ntl). Bulk-load 16 hi-B frags -> 32 MFMAs -> 16 lo-B frags ->
// 16 MFMAs. H (hi/lo bf16) double-buffered in LDS, rows 0..3 = samples.
// ---------------------------------------------------------------------------
__global__ __launch_bounds__(512, 2) void mlp_mfma(
    const float* __restrict__ h,    // (1024, 256) f32
    const short* __restrict__ wf,   // fragment-linear hi/lo bf16 weights
    const float* __restrict__ b1, const float* __restrict__ b2,
    const float* __restrict__ b3,
    float* __restrict__ out)        // (1024, 10)
{
  __shared__ short H[2][2][4][272];  // [pingpong][hi/lo][row][k] 8704 B
  const int t = threadIdx.x, lane = t & 63, wv = t >> 6;
  const int r = lane & 15, g = lane >> 4;
  const int m0 = blockIdx.x * 4;

  for (int i = t; i < 1024; i += 512) {
    const int row = i >> 8, k = i & 255;
    const float v = h[(size_t)(m0 + row) * 256 + k];
    const short hi = f2bf(v);
    H[0][0][row][k] = hi;
    H[0][1][row][k] = f2bf(v - bf2f(hi));
  }
  __syncthreads();

  int pp = 0;
  const float* bias[2] = {b1, b2};
#pragma unroll
  for (int L = 0; L < 2; ++L) {
    const short* wl = wf + L * 131072;

    bf16x8 ahi[8], alo[8];
#pragma unroll
    for (int ks = 0; ks < 8; ++ks) {
      const int ko = ks * 32 + g * 8;
      ahi[ks] = *reinterpret_cast<const bf16x8*>(&H[pp][0][r & 3][ko]);
      alo[ks] = *reinterpret_cast<const bf16x8*>(&H[pp][1][r & 3][ko]);
    }

    f32x4 acc[2];
#pragma unroll
    for (int ntl = 0; ntl < 2; ++ntl) {
      const float bv = bias[L][(wv * 2 + ntl) * 16 + r];
      f32x4 a = {bv, bv, bv, bv};
      acc[ntl] = a;
    }

    {  // hi-B bulk load, then 32 MFMAs (ahi*bhi + alo*bhi)
      bf16x8 bh[2][8];
#pragma unroll
      for (int ntl = 0; ntl < 2; ++ntl)
#pragma unroll
        for (int ks = 0; ks < 8; ++ks)
          bh[ntl][ks] = *reinterpret_cast<const bf16x8*>(
              wl + (((wv * 2 + ntl) * 8 + ks) << 9) + lane * 8);
#pragma unroll
      for (int ks = 0; ks < 8; ++ks)
#pragma unroll
        for (int ntl = 0; ntl < 2; ++ntl) {
          acc[ntl] = __builtin_amdgcn_mfma_f32_16x16x32_bf16(ahi[ks], bh[ntl][ks], acc[ntl], 0, 0, 0);
          acc[ntl] = __builtin_amdgcn_mfma_f32_16x16x32_bf16(alo[ks], bh[ntl][ks], acc[ntl], 0, 0, 0);
        }
    }
    {  // lo-B bulk load, then 16 MFMAs (ahi*blo)
      bf16x8 bl[2][8];
#pragma unroll
      for (int ntl = 0; ntl < 2; ++ntl)
#pragma unroll
        for (int ks = 0; ks < 8; ++ks)
          bl[ntl][ks] = *reinterpret_cast<const bf16x8*>(
              wl + 65536 + (((wv * 2 + ntl) * 8 + ks) << 9) + lane * 8);
#pragma unroll
      for (int ks = 0; ks < 8; ++ks)
#pragma unroll
        for (int ntl = 0; ntl < 2; ++ntl)
          acc[ntl] = __builtin_amdgcn_mfma_f32_16x16x32_bf16(ahi[ks], bl[ntl][ks], acc[ntl], 0, 0, 0);
    }

    // writeback relu(acc) hi/lo into the other buffer (rows 0..3 = g==0)
    if (g == 0) {
#pragma unroll
      for (int ntl = 0; ntl < 2; ++ntl) {
        const int col = (wv * 2 + ntl) * 16 + r;
#pragma unroll
        for (int q = 0; q < 4; ++q) {
          const float v = fmaxf(acc[ntl][q], 0.f);
          const short hi = f2bf(v);
          H[pp ^ 1][0][q][col] = hi;
          H[pp ^ 1][1][q][col] = f2bf(v - bf2f(hi));
        }
      }
    }
    __syncthreads();
    pp ^= 1;
  }

  // layer 3: one 16x16 tile (cols 10..15 zero-padded), wave 0 only
  if (wv == 0) {
    const float bv = (r < 10) ? b3[r] : 0.f;
    f32x4 acc = {bv, bv, bv, bv};
    bf16x8 ahi[8], alo[8], bh[8], bl[8];
#pragma unroll
    for (int ks = 0; ks < 8; ++ks) {
      const int ko = ks * 32 + g * 8;
      ahi[ks] = *reinterpret_cast<const bf16x8*>(&H[pp][0][r & 3][ko]);
      alo[ks] = *reinterpret_cast<const bf16x8*>(&H[pp][1][r & 3][ko]);
      bh[ks] = *reinterpret_cast<const bf16x8*>(wf + 262144 + (ks << 9) + lane * 8);
      bl[ks] = *reinterpret_cast<const bf16x8*>(wf + 262144 + 4096 + (ks << 9) + lane * 8);
    }
#pragma unroll
    for (int ks = 0; ks < 8; ++ks) {
      acc = __builtin_amdgcn_mfma_f32_16x16x32_bf16(ahi[ks], bh[ks], acc, 0, 0, 0);
      acc = __builtin_amdgcn_mfma_f32_16x16x32_bf16(alo[ks], bh[ks], acc, 0, 0, 0);
      acc = __builtin_amdgcn_mfma_f32_16x16x32_bf16(ahi[ks], bl[ks], acc, 0, 0, 0);
    }
    if (g == 0 && r < 10) {  // D rows 0..3 = samples
#pragma unroll
      for (int q = 0; q < 4; ++q)
        out[(size_t)(m0 + q) * 10 + r] = acc[q];
    }
  }
}

extern "C" void kernel_launch(void* const* d_in, const int* in_sizes, int n_in,
                              void* d_out, int out_size, void* d_ws, size_t ws_size,
                              hipStream_t stream) {
  const float* x   = (const float*)d_in[0];
  const float* cw0 = (const float*)d_in[1];
  const float* cw1 = (const float*)d_in[2];
  const float* cb  = (const float*)d_in[3];
  const float* w1  = (const float*)d_in[4];
  const float* b1  = (const float*)d_in[5];
  const float* w2  = (const float*)d_in[6];
  const float* b2  = (const float*)d_in[7];
  const float* w3  = (const float*)d_in[8];
  const float* b3  = (const float*)d_in[9];
  float* out = (float*)d_out;

  float* h   = (float*)d_ws;                        // 1 MB: (1024,256) f32
  short* wfm = (short*)((char*)d_ws + (1 << 20));   // 540 KB: MLP frag weights

  conv_prep_kernel<<<640, 256, 0, stream>>>(x, cw0, cw1, cb, w1, w2, w3, h, wfm);
  mlp_mfma<<<256, 512, 0, stream>>>(h, wfm, b1, b2, b3, out);
}